// Round 6
// baseline (473.306 us; speedup 1.0000x reference)
//
#include <hip/hip_runtime.h>

typedef unsigned short u16;
typedef short short8 __attribute__((ext_vector_type(8)));
typedef float f32x4 __attribute__((ext_vector_type(4)));

// ---------------- helpers ----------------
__device__ __forceinline__ u16 f2b(float f) {
  unsigned u = __float_as_uint(f);
  u = u + 0x7FFFu + ((u >> 16) & 1u);   // round-to-nearest-even
  return (u16)(u >> 16);
}
__device__ __forceinline__ float b2f(u16 b) {
  return __uint_as_float(((unsigned)b) << 16);
}

#define ASYNC_LD16(g, l)                                                                   \
  __builtin_amdgcn_global_load_lds((const __attribute__((address_space(1))) void*)(g),     \
                                   (__attribute__((address_space(3))) void*)(l), 16, 0, 0)

// raw barrier with compiler memory fences on both sides
#define BAR()                                  \
  do {                                         \
    asm volatile("" ::: "memory");             \
    __builtin_amdgcn_s_barrier();              \
    asm volatile("" ::: "memory");             \
  } while (0)

// ---------------- K0a: x fp32 -> bf16 ----------------
__global__ void convert_x(const float* __restrict__ x, u16* __restrict__ xb) {
  size_t i = ((size_t)blockIdx.x * 256 + threadIdx.x) * 4;
  float4 f = *(const float4*)(x + i);
  ushort4 o;
  o.x = f2b(f.x); o.y = f2b(f.y); o.z = f2b(f.z); o.w = f2b(f.w);
  *(ushort4*)(xb + i) = o;
}

// ---------------- K0b: weights fp32 -> bf16 (natural [o][e] layout) ----------------
__global__ void convert_w(const float* __restrict__ Wq, const float* __restrict__ Wk,
                          const float* __restrict__ Wv, const float* __restrict__ Wo,
                          u16* __restrict__ Wqkv, u16* __restrict__ Wob) {
  int idx = (blockIdx.x * 256 + threadIdx.x) * 4;
  int row = idx >> 9;
  int col = idx & 511;
  const float* src = (row < 512)    ? Wq + (size_t)row * 512
                     : (row < 1024) ? Wk + (size_t)(row - 512) * 512
                     : (row < 1536) ? Wv + (size_t)(row - 1024) * 512
                                    : Wo + (size_t)(row - 1536) * 512;
  u16* dst = (row < 1536) ? Wqkv + (size_t)row * 512 : Wob + (size_t)(row - 1536) * 512;
  float4 f = *(const float4*)(src + col);
  ushort4 o;
  o.x = f2b(f.x); o.y = f2b(f.y); o.z = f2b(f.z); o.w = f2b(f.w);
  *(ushort4*)(dst + col) = o;
}

// ============ 256x256 8-phase pipelined GEMM core (m201 port; K1 and K3) ============
// (unchanged from R4 — see comments there)

#define LDSV(off) (*(const short8*)&S[(off)])

#define STG(gp, scol, dst)                              \
  do {                                                  \
    ASYNC_LD16((gp) + (scol), S + (dst));               \
    ASYNC_LD16((gp) + (scol) + 4096, S + (dst) + 512);  \
  } while (0)

#define MFMA_CL(MB, JB)                                                                     \
  do {                                                                                      \
    __builtin_amdgcn_s_setprio(1);                                                          \
    _Pragma("unroll") for (int m_ = 0; m_ < 4; ++m_)                                        \
      _Pragma("unroll") for (int j_ = 0; j_ < 2; ++j_) {                                    \
        acc[(MB) + m_][(JB) + j_] = __builtin_amdgcn_mfma_f32_16x16x32_bf16(                \
            aq[m_][0], bf[(JB) + j_][0], acc[(MB) + m_][(JB) + j_], 0, 0, 0);               \
        acc[(MB) + m_][(JB) + j_] = __builtin_amdgcn_mfma_f32_16x16x32_bf16(                \
            aq[m_][1], bf[(JB) + j_][1], acc[(MB) + m_][(JB) + j_], 0, 0, 0);               \
      }                                                                                     \
    __builtin_amdgcn_s_setprio(0);                                                          \
  } while (0)

#define KSTEP(BUF, SG1, SG2, SG3, SG4, BND)                                                  \
  do {                                                                                       \
    short8 aq[4][2], bf[4][2];                                                               \
    _Pragma("unroll") for (int m_ = 0; m_ < 4; ++m_) {                                       \
      aq[m_][0] = LDSV((BUF) + rA0 + m_ * 1024);                                             \
      aq[m_][1] = LDSV((BUF) + rA1 + m_ * 1024);                                             \
    }                                                                                        \
    _Pragma("unroll") for (int j_ = 0; j_ < 2; ++j_) {                                       \
      bf[j_][0] = LDSV((BUF) + rB0 + j_ * 1024);                                             \
      bf[j_][1] = LDSV((BUF) + rB1 + j_ * 1024);                                             \
    }                                                                                        \
    SG1;                                                                                     \
    BAR(); MFMA_CL(0, 0); BAR();                                                             \
    _Pragma("unroll") for (int j_ = 0; j_ < 2; ++j_) {                                       \
      bf[2 + j_][0] = LDSV((BUF) + rB0 + (2 + j_) * 1024);                                   \
      bf[2 + j_][1] = LDSV((BUF) + rB1 + (2 + j_) * 1024);                                   \
    }                                                                                        \
    SG2; BAR(); MFMA_CL(0, 2); BAR();                                                        \
    _Pragma("unroll") for (int m_ = 0; m_ < 4; ++m_) {                                       \
      aq[m_][0] = LDSV((BUF) + rA0 + (4 + m_) * 1024);                                       \
      aq[m_][1] = LDSV((BUF) + rA1 + (4 + m_) * 1024);                                       \
    }                                                                                        \
    SG3; BAR(); MFMA_CL(4, 2); BAR();                                                        \
    SG4; BAR(); MFMA_CL(4, 0); BND; BAR();                                                   \
  } while (0)

#define GEMM8_LOOP()                                                                         \
  STG(gB0, 0, dB0); STG(gB1, 0, dB1);                                                        \
  STG(gA0, 0, dA0); STG(gA1, 0, dA1);                                                        \
  STG(gB0, 64, 32768 + dB0); STG(gB1, 64, 32768 + dB1);                                      \
  asm volatile("s_waitcnt vmcnt(4)" ::: "memory");                                           \
  BAR();                                                                                     \
  _Pragma("unroll") for (int i = 0; i < 4; ++i) {                                            \
    const int s1c = (2 * i + 1) * 64, s2c = (2 * i + 2) * 64, s3c = (2 * i + 3) * 64;        \
    if (i < 3) {                                                                             \
      KSTEP(0,                                                                               \
            STG(gA0, s1c, 32768 + dA0),                                                      \
            STG(gA1, s1c, 32768 + dA1),                                                      \
            STG(gB0, s2c, dB0),                                                              \
            STG(gB1, s2c, dB1),                                                              \
            asm volatile("s_waitcnt vmcnt(4)" ::: "memory"));                                \
      KSTEP(32768,                                                                           \
            STG(gA0, s2c, dA0),                                                              \
            STG(gA1, s2c, dA1),                                                              \
            STG(gB0, s3c, 32768 + dB0),                                                      \
            STG(gB1, s3c, 32768 + dB1),                                                      \
            asm volatile("s_waitcnt vmcnt(4)" ::: "memory"));                                \
    } else {                                                                                 \
      KSTEP(0,                                                                               \
            STG(gA0, s1c, 32768 + dA0),                                                      \
            STG(gA1, s1c, 32768 + dA1),                                                      \
            (void)0, (void)0,                                                                \
            asm volatile("s_waitcnt vmcnt(0)" ::: "memory"));                                \
      KSTEP(32768, (void)0, (void)0, (void)0, (void)0, (void)0);                             \
    }                                                                                        \
  }

// ---------------- K1: fused QKV projection ----------------
__global__ __launch_bounds__(512, 2) void gemm_qkv(
    const u16* __restrict__ xb, const u16* __restrict__ Wqkv,
    const float* __restrict__ bq, const float* __restrict__ bk,
    const float* __restrict__ bv, u16* __restrict__ Qb,
    u16* __restrict__ Ktg, u16* __restrict__ Vtg) {
  __shared__ u16 S[65536];
  const int tid = threadIdx.x;
  const int bid = blockIdx.x;
  const int wg = (bid & 7) * 192 + (bid >> 3);
  const int mtile = wg / 6;
  const int ntile = wg - mtile * 6;
  const int blockM = mtile << 8;
  const int blockN = ntile << 8;

  const int lane = tid & 63;
  const int w = tid >> 6;
  const int wm = (w >> 2) << 7;
  const int wn = (w & 3) << 6;
  const int lr = lane & 15;
  const int qd = lane >> 4;
  const int r7 = lr & 7;
  const int l8 = lane >> 3;
  const int l7 = lane & 7;

  const int gsw8 = (l7 ^ l8) * 8;
  const u16* gA0 = xb + (size_t)(blockM + w * 16 + l8) * 512 + gsw8;
  const u16* gA1 = gA0 + 128 * 512;
  const u16* gB0 = Wqkv + (size_t)(blockN + w * 16 + l8) * 512 + gsw8;
  const u16* gB1 = gB0 + 128 * 512;
  const int dA0 = (w * 16 + l8) * 64 + l7 * 8;
  const int dA1 = dA0 + 8192;
  const int dB0 = dA0 + 16384;
  const int dB1 = dA0 + 24576;

  const int rA0 = (wm + lr) * 64 + ((qd) ^ r7) * 8;
  const int rA1 = (wm + lr) * 64 + ((qd + 4) ^ r7) * 8;
  const int rB0 = 16384 + (wn + lr) * 64 + ((qd) ^ r7) * 8;
  const int rB1 = 16384 + (wn + lr) * 64 + ((qd + 4) ^ r7) * 8;

  f32x4 acc[8][4];
#pragma unroll
  for (int m = 0; m < 8; ++m)
#pragma unroll
    for (int j = 0; j < 4; ++j) acc[m][j] = {0.f, 0.f, 0.f, 0.f};

  GEMM8_LOOP();

  const int which = blockN >> 9;
  const int cb = blockN & 511;
  if (which == 0) {
#pragma unroll
    for (int j = 0; j < 4; ++j) {
      int col = cb + wn + j * 16 + lr;
      float bsv = bq[col];
#pragma unroll
      for (int m = 0; m < 8; ++m) {
        int row = blockM + wm + m * 16 + qd * 4;
#pragma unroll
        for (int r = 0; r < 4; ++r) {
          float v = acc[m][j][r] + bsv;
          v = (v > 0.f) ? v + 1.f : __expf(v);
          Qb[(size_t)(row + r) * 512 + col] = f2b(v);
        }
      }
    }
  } else {
    u16* dstT = (which == 1) ? Ktg : Vtg;
    const float* bias = (which == 1) ? bk : bv;
    const int br = blockM >> 9;
    const int t0 = (blockM & 511) + wm;
#pragma unroll
    for (int j = 0; j < 4; ++j) {
      int col = cb + wn + j * 16 + lr;
      float bsv = bias[col];
      size_t rowbase = (size_t)br * 262144 + (size_t)col * 512;
#pragma unroll
      for (int m = 0; m < 8; ++m) {
        int c0 = t0 + m * 16 + qd * 4;
        float v0 = acc[m][j][0] + bsv, v1 = acc[m][j][1] + bsv;
        float v2 = acc[m][j][2] + bsv, v3 = acc[m][j][3] + bsv;
        if (which == 1) {
          v0 = (v0 > 0.f) ? v0 + 1.f : __expf(v0);
          v1 = (v1 > 0.f) ? v1 + 1.f : __expf(v1);
          v2 = (v2 > 0.f) ? v2 + 1.f : __expf(v2);
          v3 = (v3 > 0.f) ? v3 + 1.f : __expf(v3);
        }
        ushort4 p;
        p.x = f2b(v0); p.y = f2b(v1); p.z = f2b(v2); p.w = f2b(v3);
        *(ushort4*)&dstT[rowbase + c0] = p;
      }
    }
  }
}

// ---------------- K2: attn (R5 structure + prologue vmcnt-order fix) ----------------
// Per (br,h) block, 256 threads = 4 waves.
// Phase A: ktv = K^T V over 8 chunks of 64 tokens. K -> registers; V -> LDS
// double-buffered + granule-swizzled; counted vmcnt. ksum via MFMA with ones-B.
// Phase B: out = (Q @ ktv) * z, z in-register via shfl. No barriers in phase B.
// FIX vs R5: compiler fence pins the prologue issue order (V0,V1 builtins BEFORE
// the plain ka loads) so vmcnt(4) provably drains V0 — without it the compiler
// can hoist the scalar K loads above the global_load_lds builtins, and vmcnt(4)
// then retires K0 instead of V0 (race on VtS[0], sparse stale granules).
__global__ __launch_bounds__(256) void attn(const u16* __restrict__ Qb,
                                            const u16* __restrict__ Ktg,
                                            const u16* __restrict__ Vtg,
                                            u16* __restrict__ Hb) {
  __shared__ u16 VtS[2][4096];      // [buf][e 64][c 64, granule-swizzled]  16 KB
  __shared__ u16 ktvT[2 * 64 * 32]; // [kc][e][32 d]  8 KB
  __shared__ float ksumf[64];

  const int tid = threadIdx.x;
  const int br = blockIdx.x >> 3;
  const int h = blockIdx.x & 7;
  const int h64 = h * 64;
  const size_t tok0 = (size_t)br * 512;
  const size_t tbase = (size_t)br * 262144 + (size_t)h64 * 512;

  const int lane = tid & 63;
  const int w = tid >> 6;   // 4 waves, wave w owns d-strip / token-strip w*16
  const int lr = lane & 15;
  const int qd = lane >> 4;

  // V staging: inst i in {0,1}: row e = i*32 + (tid>>3), dest u16 = i*2048 + tid*8,
  // src granule = (tid&7) ^ ((tid>>3)&7)  (involution matching read side)
  const int sgi = (tid & 7) ^ ((tid >> 3) & 7);
  const u16* gV = Vtg + tbase + (size_t)(tid >> 3) * 512 + sgi * 8;

#define STGV(buf, ct)                                              \
  do {                                                             \
    ASYNC_LD16(gV + (ct) * 64, &VtS[buf][tid * 8]);                \
    ASYNC_LD16(gV + 16384 + (ct) * 64, &VtS[buf][2048 + tid * 8]); \
  } while (0)

  // b-frag read granules: (csub*4+qd) ^ (lr&7)
  const int g0 = ((qd) ^ (lane & 7)) * 8;
  const int g1 = ((qd + 4) ^ (lane & 7)) * 8;

  // K direct-to-reg: lane (lr,qd) reads K^T[w*16+lr][ct*64 + csub*32 + qd*8 ..+8]
  const u16* gK = Ktg + tbase + (size_t)(w * 16 + lr) * 512 + qd * 8;

  short8 ones;
#pragma unroll
  for (int i = 0; i < 8; ++i) ones[i] = (short)0x3F80;

  f32x4 acc[4];
  f32x4 aks = {0.f, 0.f, 0.f, 0.f};
#pragma unroll
  for (int j = 0; j < 4; ++j) acc[j] = {0.f, 0.f, 0.f, 0.f};

  // ---------- phase A ----------
  STGV(0, 0);
  STGV(1, 1);
  asm volatile("" ::: "memory");  // FIX: pin V0,V1 issue before the plain K loads
  short8 ka0 = *(const short8*)(gK);
  short8 ka1 = *(const short8*)(gK + 32);
  asm volatile("s_waitcnt vmcnt(4)" ::: "memory");  // order pinned -> drains V0
  BAR();

#pragma unroll
  for (int ct = 0; ct < 8; ++ct) {
    const int buf = ct & 1;
    short8 kn0, kn1;
    if (ct < 7) {
      kn0 = *(const short8*)(gK + (ct + 1) * 64);
      kn1 = *(const short8*)(gK + (ct + 1) * 64 + 32);
    }
    // csub 0
    aks = __builtin_amdgcn_mfma_f32_16x16x32_bf16(ka0, ones, aks, 0, 0, 0);
#pragma unroll
    for (int j = 0; j < 4; ++j) {
      short8 b = *(const short8*)&VtS[buf][(j * 16 + lr) * 64 + g0];
      acc[j] = __builtin_amdgcn_mfma_f32_16x16x32_bf16(ka0, b, acc[j], 0, 0, 0);
    }
    // csub 1
    aks = __builtin_amdgcn_mfma_f32_16x16x32_bf16(ka1, ones, aks, 0, 0, 0);
#pragma unroll
    for (int j = 0; j < 4; ++j) {
      short8 b = *(const short8*)&VtS[buf][(j * 16 + lr) * 64 + g1];
      acc[j] = __builtin_amdgcn_mfma_f32_16x16x32_bf16(ka1, b, acc[j], 0, 0, 0);
    }
    BAR();  // all waves done reading VtS[buf]
    if (ct < 6) {
      STGV(buf, ct + 2);
      asm volatile("s_waitcnt vmcnt(4)" ::: "memory");  // V(ct+1) landed
    } else if (ct == 6) {
      asm volatile("s_waitcnt vmcnt(2)" ::: "memory");  // V7 landed (K7 in flight)
    }
    BAR();
    if (ct < 7) { ka0 = kn0; ka1 = kn1; }
  }

  // ktv -> ktvT (bf16), layout [kc = w>>1][e][d' = (w&1)*16 + qd*4 + r]
  {
    int kc = w >> 1;
    int dp = (w & 1) * 16 + qd * 4;
#pragma unroll
    for (int j = 0; j < 4; ++j) {
      int e = j * 16 + lr;
      ushort4 p;
      p.x = f2b(acc[j][0]); p.y = f2b(acc[j][1]);
      p.z = f2b(acc[j][2]); p.w = f2b(acc[j][3]);
      *(ushort4*)&ktvT[kc * 2048 + e * 32 + dp] = p;
    }
  }
  // ksum: aks reg r = D[qd*4+r][lr] = ksum[w*16 + qd*4 + r]; lanes lr==0 write
  if (lr == 0) {
#pragma unroll
    for (int r = 0; r < 4; ++r) ksumf[w * 16 + qd * 4 + r] = aks[r];
  }
  __syncthreads();

  // hoists: ktv B-frags + ksum slices
  short8 bfr[4][2];
#pragma unroll
  for (int j = 0; j < 4; ++j)
#pragma unroll
    for (int kc = 0; kc < 2; ++kc)
      bfr[j][kc] = *(const short8*)&ktvT[kc * 2048 + (j * 16 + lr) * 32 + qd * 8];
  float ksf0[8], ksf1[8];
#pragma unroll
  for (int i = 0; i < 8; ++i) {
    ksf0[i] = ksumf[qd * 8 + i];
    ksf1[i] = ksumf[32 + qd * 8 + i];
  }

  // ---------- phase B: no barriers, no LDS ----------
  const u16* gQ = Qb + (tok0 + w * 16 + lr) * 512 + h64 + qd * 8;
  short8 qa0 = *(const short8*)(gQ);
  short8 qa1 = *(const short8*)(gQ + 32);

#pragma unroll
  for (int ct = 0; ct < 8; ++ct) {
    short8 qn0, qn1;
    if (ct < 7) {
      qn0 = *(const short8*)(gQ + (size_t)(ct + 1) * 32768);
      qn1 = *(const short8*)(gQ + (size_t)(ct + 1) * 32768 + 32);
    }
    // z = 1/(q . ksum): per-lane partial over its 16 k-elems, reduce over qd groups
    float dot = 0.f;
#pragma unroll
    for (int i = 0; i < 8; ++i) {
      dot += b2f((u16)qa0[i]) * ksf0[i];
      dot += b2f((u16)qa1[i]) * ksf1[i];
    }
    dot += __shfl_xor(dot, 16);
    dot += __shfl_xor(dot, 32);
    float z = 1.f / (dot + 1e-6f);

    f32x4 o[4];
#pragma unroll
    for (int j = 0; j < 4; ++j) {
      o[j] = {0.f, 0.f, 0.f, 0.f};
      o[j] = __builtin_amdgcn_mfma_f32_16x16x32_bf16(qa0, bfr[j][0], o[j], 0, 0, 0);
      o[j] = __builtin_amdgcn_mfma_f32_16x16x32_bf16(qa1, bfr[j][1], o[j], 0, 0, 0);
    }
    // z for output rows qd*4+r lives at lane (qd*4+r)
    float z0 = __shfl(z, qd * 4 + 0);
    float z1 = __shfl(z, qd * 4 + 1);
    float z2 = __shfl(z, qd * 4 + 2);
    float z3 = __shfl(z, qd * 4 + 3);
    size_t gb = (tok0 + ct * 64 + w * 16 + qd * 4) * 512 + h64;
#pragma unroll
    for (int j = 0; j < 4; ++j) {
      int e = j * 16 + lr;
      Hb[gb + e] = f2b(o[j][0] * z0);
      Hb[gb + 512 + e] = f2b(o[j][1] * z1);
      Hb[gb + 1024 + e] = f2b(o[j][2] * z2);
      Hb[gb + 1536 + e] = f2b(o[j][3] * z3);
    }
    if (ct < 7) { qa0 = qn0; qa1 = qn1; }
  }
#undef STGV
}

// ---------------- K3: out = out_h @ Wo^T + bo (fp32 out) ----------------
__global__ __launch_bounds__(512, 2) void gemm_out(
    const u16* __restrict__ Hb, const u16* __restrict__ Wob,
    const float* __restrict__ bo, float* __restrict__ out) {
  __shared__ u16 S[65536];
  const int tid = threadIdx.x;
  const int bid = blockIdx.x;
  const int wg = (bid & 7) * 64 + (bid >> 3);
  const int mtile = wg >> 1;
  const int ntile = wg & 1;
  const int blockM = mtile << 8;
  const int blockN = ntile << 8;

  const int lane = tid & 63;
  const int w = tid >> 6;
  const int wm = (w >> 2) << 7;
  const int wn = (w & 3) << 6;
  const int lr = lane & 15;
  const int qd = lane >> 4;
  const int r7 = lr & 7;
  const int l8 = lane >> 3;
  const int l7 = lane & 7;

  const int gsw8 = (l7 ^ l8) * 8;
  const u16* gA0 = Hb + (size_t)(blockM + w * 16 + l8) * 512 + gsw8;
  const u16* gA1 = gA0 + 128 * 512;
  const u16* gB0 = Wob + (size_t)(blockN + w * 16 + l8) * 512 + gsw8;
  const u16* gB1 = gB0 + 128 * 512;
  const int dA0 = (w * 16 + l8) * 64 + l7 * 8;
  const int dA1 = dA0 + 8192;
  const int dB0 = dA0 + 16384;
  const int dB1 = dA0 + 24576;

  const int rA0 = (wm + lr) * 64 + ((qd) ^ r7) * 8;
  const int rA1 = (wm + lr) * 64 + ((qd + 4) ^ r7) * 8;
  const int rB0 = 16384 + (wn + lr) * 64 + ((qd) ^ r7) * 8;
  const int rB1 = 16384 + (wn + lr) * 64 + ((qd + 4) ^ r7) * 8;

  f32x4 acc[8][4];
#pragma unroll
  for (int m = 0; m < 8; ++m)
#pragma unroll
    for (int j = 0; j < 4; ++j) acc[m][j] = {0.f, 0.f, 0.f, 0.f};

  GEMM8_LOOP();

#pragma unroll
  for (int j = 0; j < 4; ++j) {
    int col = blockN + wn + j * 16 + lr;
    float bsv = bo[col];
#pragma unroll
    for (int m = 0; m < 8; ++m) {
      int row = blockM + wm + m * 16 + qd * 4;
#pragma unroll
      for (int r = 0; r < 4; ++r)
        out[(size_t)(row + r) * 512 + col] = acc[m][j][r] + bsv;
    }
  }
}

// ---------------- launch ----------------
extern "C" void kernel_launch(void* const* d_in, const int* in_sizes, int n_in,
                              void* d_out, int out_size, void* d_ws, size_t ws_size,
                              hipStream_t stream) {
  const float* x  = (const float*)d_in[0];
  const float* Wq = (const float*)d_in[1];
  const float* bq = (const float*)d_in[2];
  const float* Wk = (const float*)d_in[3];
  const float* bk = (const float*)d_in[4];
  const float* Wv = (const float*)d_in[5];
  const float* bv = (const float*)d_in[6];
  const float* Wo = (const float*)d_in[7];
  const float* bo = (const float*)d_in[8];
  float* out = (float*)d_out;

  char* ws = (char*)d_ws;
  u16* xb   = (u16*)(ws);                 // 64 MB  (reused as Hb)
  u16* Wqkv = (u16*)(ws + 0x04000000ull); // 1.5 MB
  u16* Wob  = (u16*)(ws + 0x04200000ull); // 0.5 MB
  u16* Qb   = (u16*)(ws + 0x04400000ull); // 64 MB
  u16* Ktg  = (u16*)(ws + 0x08400000ull); // 64 MB [br][chan][tok]
  u16* Vtg  = (u16*)(ws + 0x0C400000ull); // 64 MB [br][chan][tok]
  u16* Hb   = xb;

  hipLaunchKernelGGL(convert_x, dim3(32768), dim3(256), 0, stream, x, xb);
  hipLaunchKernelGGL(convert_w, dim3(1024), dim3(256), 0, stream, Wq, Wk, Wv, Wo, Wqkv, Wob);
  hipLaunchKernelGGL(gemm_qkv, dim3(1536), dim3(512), 0, stream, xb, Wqkv, bq, bk, bv, Qb, Ktg, Vtg);
  hipLaunchKernelGGL(attn, dim3(1024), dim3(256), 0, stream, Qb, Ktg, Vtg, Hb);
  hipLaunchKernelGGL(gemm_out, dim3(512), dim3(512), 0, stream, Hb, Wob, bo, out);
}